// Round 5
// baseline (139.055 us; speedup 1.0000x reference)
//
#include <hip/hip_runtime.h>

// Grouped GEMM a[16384,512] x b[8][512,512] (fp32) -> fp32.
// R5: barrier-free GEMM. Phase 1 transposes/converts B to bf16 [g][n][k]
// (13 MB, ~2us). Phase 2 GEMM has NO LDS and NO __syncthreads: each lane
// loads its MFMA fragments directly from global (A fp32 + in-register cvt,
// B bf16 L2-resident), 2-phase register ping-pong so next k-step's loads
// are in flight during current MFMAs. Sidesteps the vmcnt(0)-drain at
// __syncthreads that capped the LDS-staged structure (R2, ~21us kernel).

#define KDIM 512
#define NDIM 512
#define BM 128
#define BN 128

typedef __bf16 bf16x8 __attribute__((ext_vector_type(8)));
typedef __bf16 bf16x4 __attribute__((ext_vector_type(4)));
typedef float  f32x4  __attribute__((ext_vector_type(4)));

// ---------------- P1: B [g][k][n] fp32 -> bf16 [g][n][k] (verified in R3) ----
#define TSTRIDE 68
__global__ __launch_bounds__(256)
void cvtB_kernel(const float* __restrict__ B, __bf16* __restrict__ Bt) {
    __shared__ __bf16 tile[64 * TSTRIDE];
    const int bid = blockIdx.x;
    const int g  = bid >> 6;
    const int kt = (bid >> 3) & 7;
    const int nt = bid & 7;
    const int k0 = kt * 64, n0 = nt * 64;
    const int t = threadIdx.x;

    const int rk = (t >> 4) * 4;
    const int rn = (t & 15) * 4;
#pragma unroll
    for (int dk = 0; dk < 4; ++dk) {
        f32x4 v = *(const f32x4*)(B + (size_t)(g * KDIM + k0 + rk + dk) * NDIM + n0 + rn);
        bf16x4 w;
        w[0] = (__bf16)v[0]; w[1] = (__bf16)v[1]; w[2] = (__bf16)v[2]; w[3] = (__bf16)v[3];
        *(bf16x4*)&tile[(rk + dk) * TSTRIDE + rn] = w;
    }
    __syncthreads();
    const int on = t >> 2;
    const int kc = (t & 3) * 16;
    bf16x8 o0, o1;
#pragma unroll
    for (int j = 0; j < 8; ++j) o0[j] = tile[(kc + j) * TSTRIDE + on];
#pragma unroll
    for (int j = 0; j < 8; ++j) o1[j] = tile[(kc + 8 + j) * TSTRIDE + on];
    __bf16* dst = Bt + (size_t)(g * NDIM + n0 + on) * KDIM + k0 + kc;
    *(bf16x8*)dst = o0;
    *(bf16x8*)(dst + 8) = o1;
}

// ---------------- P2: barrier-free direct-fragment GEMM ----------------
__global__ __launch_bounds__(256, 2)
void gemm_kernel(const float* __restrict__ A, const __bf16* __restrict__ Bt,
                 const int* __restrict__ glist, float* __restrict__ C, int G) {
    const int b  = blockIdx.x;
    const int tm = b >> 2;
    const int tn = b & 3;
    const int row0 = tm * BM;
    const int col0 = tn * BN;

    int gid = 0;
    for (int g = 0; g < G; ++g) gid += (glist[g] <= row0) ? 1 : 0;

    const int t    = threadIdx.x;
    const int lane = t & 63;
    const int wave = t >> 6;
    const int lm   = lane & 15;
    const int quad = lane >> 4;
    const int wm   = wave >> 1;
    const int wn   = wave & 1;

    // Fragment base pointers: lane (lm,quad) owns row/col lm, k = quad*8..+7.
    const float*  aB = A  + (size_t)(row0 + wm * 64 + lm) * KDIM + quad * 8;
    const __bf16* bB = Bt + ((size_t)gid * NDIM + col0 + wn * 64 + lm) * KDIM + quad * 8;

    f32x4  ar[2][4][2];   // [phase][i-frag][half]: 8 fp32 of A per frag
    bf16x8 br[2][4];      // [phase][j-frag]: 8 bf16 of B per frag
    f32x4  acc[4][4];
#pragma unroll
    for (int i = 0; i < 4; ++i)
#pragma unroll
        for (int j = 0; j < 4; ++j)
            acc[i][j] = (f32x4){0.f, 0.f, 0.f, 0.f};

#define LOADP(p, kt) do {                                                  \
        const int k0_ = (kt) * 32;                                         \
        _Pragma("unroll")                                                  \
        for (int i_ = 0; i_ < 4; ++i_) {                                   \
            const float* pa_ = aB + (size_t)i_ * 16 * KDIM + k0_;          \
            ar[p][i_][0] = *(const f32x4*)pa_;                             \
            ar[p][i_][1] = *(const f32x4*)(pa_ + 4);                       \
        }                                                                  \
        _Pragma("unroll")                                                  \
        for (int j_ = 0; j_ < 4; ++j_)                                     \
            br[p][j_] = *(const bf16x8*)(bB + (size_t)j_ * 16 * KDIM + k0_);\
    } while (0)

#define MFMAP(p) do {                                                      \
        _Pragma("unroll")                                                  \
        for (int i_ = 0; i_ < 4; ++i_) {                                   \
            bf16x8 af_;                                                    \
            af_[0] = (__bf16)ar[p][i_][0][0]; af_[1] = (__bf16)ar[p][i_][0][1]; \
            af_[2] = (__bf16)ar[p][i_][0][2]; af_[3] = (__bf16)ar[p][i_][0][3]; \
            af_[4] = (__bf16)ar[p][i_][1][0]; af_[5] = (__bf16)ar[p][i_][1][1]; \
            af_[6] = (__bf16)ar[p][i_][1][2]; af_[7] = (__bf16)ar[p][i_][1][3]; \
            _Pragma("unroll")                                              \
            for (int j_ = 0; j_ < 4; ++j_)                                 \
                acc[i_][j_] = __builtin_amdgcn_mfma_f32_16x16x32_bf16(     \
                    af_, br[p][j_], acc[i_][j_], 0, 0, 0);                 \
        }                                                                  \
    } while (0)

    LOADP(0, 0);
#pragma unroll
    for (int kt = 0; kt < KDIM / 32; kt += 2) {   // 16 k-steps, 2 per iter
        if (kt + 1 < KDIM / 32) LOADP(1, kt + 1);
        MFMAP(0);
        if (kt + 2 < KDIM / 32) LOADP(0, kt + 2);
        MFMAP(1);
    }
#undef LOADP
#undef MFMAP

    // ---- epilogue: C/D layout col=lane&15, row=quad*4+reg ----
#pragma unroll
    for (int i = 0; i < 4; ++i) {
        const int gr0 = row0 + wm * 64 + i * 16 + quad * 4;
#pragma unroll
        for (int j = 0; j < 4; ++j) {
            const int gc = col0 + wn * 64 + j * 16 + lm;
#pragma unroll
            for (int r = 0; r < 4; ++r)
                C[(size_t)(gr0 + r) * NDIM + gc] = acc[i][j][r];
        }
    }
}

extern "C" void kernel_launch(void* const* d_in, const int* in_sizes, int n_in,
                              void* d_out, int out_size, void* d_ws, size_t ws_size,
                              hipStream_t stream) {
    const float* a  = (const float*)d_in[0];
    const float* bw = (const float*)d_in[1];
    const int*   gl = (const int*)d_in[2];
    float* out = (float*)d_out;

    const int M = in_sizes[0] / KDIM;          // 16384
    const int G = in_sizes[2];                 // 8

    __bf16* Bt = (__bf16*)d_ws;                // G*N*K bf16 = 4.2 MB

    cvtB_kernel<<<G * 64, 256, 0, stream>>>(bw, Bt);
    gemm_kernel<<<(M / BM) * (NDIM / BN), 256, 0, stream>>>(a, Bt, gl, out, G);
}

// Round 6
// 108.740 us; speedup vs baseline: 1.2788x; 1.2788x over previous
//
#include <hip/hip_runtime.h>

// Grouped GEMM a[16384,512] x b[8][512,512] (fp32, groups of 2048 rows) -> fp32.
// R6 = R2 (best: 106.8) + XCD swizzle ONLY.
// R2 structure: 128x128 tile, BK=64, fp32->bf16 cvt in staging, dbuf LDS,
// single barrier/iter, register prefetch issued AFTER the barrier.
// R5 lesson: fragments MUST come from LDS (direct global frags are TA-issue
// bound: 64 lines/instr, MfmaUtil 4.6%). R2 residual is read traffic: A and B
// re-read 4x in fp32 (268 MB) with tn-siblings scattered across XCDs.
// Swizzle: b&7 -> XCD (dispatch round-robin heuristic); each XCD owns 16
// tm-strips + exactly one B[g]; tn innermost so the 4 blocks sharing an
// A-tile run adjacently on one XCD -> A: 1 fetch + 3 L2 hits, B[g] L2-resident.

#define KDIM 512
#define NDIM 512
#define BM 128
#define BN 128
#define BK 64
#define LDSTRIDE 72   // 64 + 8 bf16 pad (144 B rows)

typedef __bf16 bf16x8 __attribute__((ext_vector_type(8)));
typedef __bf16 bf16x4 __attribute__((ext_vector_type(4)));
typedef float  f32x4  __attribute__((ext_vector_type(4)));

__global__ __launch_bounds__(256, 2)
void grouped_gemm_kernel(const float* __restrict__ A,
                         const float* __restrict__ B,
                         const int*   __restrict__ glist,
                         float*       __restrict__ C,
                         int M, int G)
{
    __shared__ __bf16 As[2][BM * LDSTRIDE];
    __shared__ __bf16 Bs[2][BN * LDSTRIDE];

    // ---- XCD-aware swizzle (perf heuristic only) ----
    const int b   = blockIdx.x;          // 512 blocks = 8 XCD x 16 tm x 4 tn
    const int xcd = b & 7;
    const int i   = b >> 3;
    const int tm  = xcd * 16 + (i >> 2);
    const int tn  = i & 3;
    const int row0 = tm * BM;
    const int col0 = tn * BN;

    // searchsorted(group_list, row0, side='right'); tiles never straddle groups
    int gid = 0;
    for (int g = 0; g < G; ++g) gid += (glist[g] <= row0) ? 1 : 0;
    const float* Bg = B + (size_t)gid * KDIM * NDIM;

    const int t    = threadIdx.x;
    const int lane = t & 63;
    const int wave = t >> 6;
    const int wm   = wave >> 1;
    const int wn   = wave & 1;
    const int lm   = lane & 15;
    const int quad = lane >> 4;

    // A staging: 8 floats along K x 4 rows (stride 32)
    const int a_seg = t & 7;
    const int a_row = t >> 3;
    // B staging: 8 n-cols x 4 k-rows
    const int b_n0  = (t & 15) * 8;
    const int b_k0  = (t >> 4) * 4;

    const float* aptr = A + (size_t)(row0 + a_row) * KDIM + a_seg * 8;
    const float* bptr = Bg + (size_t)b_k0 * NDIM + col0 + b_n0;

    f32x4 ra[4][2], rb[4][2];

    // ---- prologue: K-tile 0 into registers ----
#pragma unroll
    for (int s = 0; s < 4; ++s) {
        const float* p = aptr + (size_t)(s * 32) * KDIM;
        ra[s][0] = *(const f32x4*)p;
        ra[s][1] = *(const f32x4*)(p + 4);
    }
#pragma unroll
    for (int dk = 0; dk < 4; ++dk) {
        const float* p = bptr + (size_t)dk * NDIM;
        rb[dk][0] = *(const f32x4*)p;
        rb[dk][1] = *(const f32x4*)(p + 4);
    }

    f32x4 acc[4][4];
#pragma unroll
    for (int ii = 0; ii < 4; ++ii)
#pragma unroll
        for (int j = 0; j < 4; ++j)
            acc[ii][j] = (f32x4){0.f, 0.f, 0.f, 0.f};

    const int NITER = KDIM / BK;               // 8
    for (int it = 0; it < NITER; ++it) {
        __bf16* as = As[it & 1];
        __bf16* bs = Bs[it & 1];

        // ---- cvt + stage A (vmcnt wait lands here) ----
#pragma unroll
        for (int s = 0; s < 4; ++s) {
            const int r = a_row + s * 32;
            bf16x8 w;
            w[0] = (__bf16)ra[s][0][0]; w[1] = (__bf16)ra[s][0][1];
            w[2] = (__bf16)ra[s][0][2]; w[3] = (__bf16)ra[s][0][3];
            w[4] = (__bf16)ra[s][1][0]; w[5] = (__bf16)ra[s][1][1];
            w[6] = (__bf16)ra[s][1][2]; w[7] = (__bf16)ra[s][1][3];
            *(bf16x8*)&as[r * LDSTRIDE + a_seg * 8] = w;
        }
        // ---- cvt + stage B transposed [n][k], 16B-granule XOR swizzle ----
#pragma unroll
        for (int dn = 0; dn < 8; ++dn) {
            const int n = b_n0 + dn;
            bf16x4 w;
#pragma unroll
            for (int dk = 0; dk < 4; ++dk)
                w[dk] = (__bf16)rb[dk][dn >> 2][dn & 3];
            const int g16  = b_k0 >> 3;
            const int half = (b_k0 >> 2) & 1;
            const int phys = g16 ^ ((n >> 3) & 7);
            *(bf16x4*)&bs[n * LDSTRIDE + phys * 8 + half * 4] = w;
        }

        __syncthreads();

        // ---- prefetch next K-tile AFTER the barrier ----
        if (it < NITER - 1) {
            const int kb = (it + 1) * BK;
#pragma unroll
            for (int s = 0; s < 4; ++s) {
                const float* p = aptr + (size_t)(s * 32) * KDIM + kb;
                ra[s][0] = *(const f32x4*)p;
                ra[s][1] = *(const f32x4*)(p + 4);
            }
#pragma unroll
            for (int dk = 0; dk < 4; ++dk) {
                const float* p = bptr + (size_t)(kb + dk) * NDIM;
                rb[dk][0] = *(const f32x4*)p;
                rb[dk][1] = *(const f32x4*)(p + 4);
            }
        }

        // ---- fragments + 32 MFMAs ----
#pragma unroll
        for (int ks = 0; ks < 2; ++ks) {
            const int g16 = ks * 4 + quad;
            bf16x8 af[4], bfr[4];
#pragma unroll
            for (int ii = 0; ii < 4; ++ii) {
                const int m = wm * 64 + ii * 16 + lm;
                af[ii] = *(const bf16x8*)&as[m * LDSTRIDE + g16 * 8];
            }
#pragma unroll
            for (int j = 0; j < 4; ++j) {
                const int n = wn * 64 + j * 16 + lm;
                const int phys = g16 ^ ((n >> 3) & 7);
                bfr[j] = *(const bf16x8*)&bs[n * LDSTRIDE + phys * 8];
            }
#pragma unroll
            for (int ii = 0; ii < 4; ++ii)
#pragma unroll
                for (int j = 0; j < 4; ++j)
                    acc[ii][j] = __builtin_amdgcn_mfma_f32_16x16x32_bf16(
                        af[ii], bfr[j], acc[ii][j], 0, 0, 0);
        }
    }

    // ---- epilogue: C/D layout col=lane&15, row=quad*4+reg ----
#pragma unroll
    for (int ii = 0; ii < 4; ++ii) {
        const int gr0 = row0 + wm * 64 + ii * 16 + quad * 4;
#pragma unroll
        for (int j = 0; j < 4; ++j) {
            const int gc = col0 + wn * 64 + j * 16 + lm;
#pragma unroll
            for (int r = 0; r < 4; ++r)
                C[(size_t)(gr0 + r) * NDIM + gc] = acc[ii][j][r];
        }
    }
}

extern "C" void kernel_launch(void* const* d_in, const int* in_sizes, int n_in,
                              void* d_out, int out_size, void* d_ws, size_t ws_size,
                              hipStream_t stream) {
    const float* a  = (const float*)d_in[0];
    const float* bw = (const float*)d_in[1];
    const int*   gl = (const int*)d_in[2];
    float* out = (float*)d_out;

    const int M = in_sizes[0] / KDIM;          // 16384
    const int G = in_sizes[2];                 // 8

    dim3 grid((M / BM) * (NDIM / BN));         // 512 blocks
    grouped_gemm_kernel<<<grid, 256, 0, stream>>>(a, bw, gl, out, M, G);
}